// Round 1
// baseline (5459.548 us; speedup 1.0000x reference)
//
#include <hip/hip_runtime.h>

using u16    = unsigned short;
using u64_t  = unsigned long long;
using short4v = __attribute__((ext_vector_type(4))) short;
using short8 = __attribute__((ext_vector_type(8))) short;
using f32x4  = __attribute__((ext_vector_type(4))) float;

#define T_STEPS 512
#define BATCH   128
#define HDIM    512
#define EDIM    256
#define NWG     256
#define WGS     256
// packed h: [slot(4)][cg(64)][row(128)][8 cols] bf16 -> 64*128*8 u16 per slot
#define HPITCH  65536
#define NSLOT   4

__device__ __forceinline__ u16 f2bf(float f) {
  unsigned u = __float_as_uint(f);
  u += 0x7FFFu + ((u >> 16) & 1u);   // RNE
  return (u16)(u >> 16);
}
__device__ __forceinline__ float bf2f(u16 h) {
  return __uint_as_float(((unsigned)h) << 16);
}
__device__ __forceinline__ float sigm(float x) { return 1.0f / (1.0f + __expf(-x)); }
__device__ __forceinline__ float ftanh(float x) { return 1.0f - 2.0f / (__expf(2.0f * x) + 1.0f); }

// ---- coherent (agent-scope, sc0|sc1) accessors: LLC-coherent, no L2 flush ----
__device__ __forceinline__ u64_t cl8(const u16* p) {
  return __hip_atomic_load((const u64_t*)p, __ATOMIC_RELAXED, __HIP_MEMORY_SCOPE_AGENT);
}
__device__ __forceinline__ void cstore2(u16* p, u16 v) {
  __hip_atomic_store(p, v, __ATOMIC_RELAXED, __HIP_MEMORY_SCOPE_AGENT);
}
__device__ __forceinline__ short8 mk8(u64_t lo, u64_t hi) {
  short4v a = __builtin_bit_cast(short4v, lo);
  short4v b = __builtin_bit_cast(short4v, hi);
  return __builtin_shufflevector(a, b, 0, 1, 2, 3, 4, 5, 6, 7);
}

// ---------------- x -> bf16 prep ----------------
__global__ void cvt_bf16_kernel(const float* __restrict__ src, u16* __restrict__ dst, int n4) {
  int i = blockIdx.x * blockDim.x + threadIdx.x;
  if (i >= n4) return;
  float4 v = ((const float4*)src)[i];
  uint2 o;
  o.x = (unsigned)f2bf(v.x) | ((unsigned)f2bf(v.y) << 16);
  o.y = (unsigned)f2bf(v.z) | ((unsigned)f2bf(v.w) << 16);
  ((uint2*)dst)[i] = o;
}

// ---------------- persistent 2-layer LSTM, stamp-synchronized ----------------
// No grid barrier. Dependency graph is wave-granular: consumer wave w of group
// (layer,m) reads ONLY rows w*16..w*16+15 of every producer block, i.e. only
// producer wave w of the 64 WGs in group m. So sync is per-(m,nc,w) monotone
// stamps (= completed steps) + depth-4 h ring buffers.
//   stamp entry (m,w,nc) = 8B at ((m*4+w)*64+nc)*8 : {S0 (layer0), S1 (layer1)}
//   (each (m,w) group = contiguous 512B -> a consumer wave's 64-lane poll is
//    one coalesced 4-line load; producers store 4B each into those 4 lines)
// Waits (stamp value = steps completed; producer stores t+1 after step t):
//   L0 step t: S0[*]>=t   (own group h0[t-1])  && S1[*]>=t-3 (slot t&3 reuse)
//   L1 step t: S0[*]>=t+1 (h0[t] ready)        && S1[*]>=t   (own h1[t-1])
// Producer: h stores -> s_waitcnt vmcnt(0) (wave-wide drain, stores LLC-visible,
// same mechanism the verified barrier kernel relied on) -> lane0 relaxed stamp.
__global__ void __launch_bounds__(WGS, 1) lstm_kernel(
    const float* __restrict__ wih0, const float* __restrict__ whh0,
    const float* __restrict__ bih0, const float* __restrict__ bhh0,
    const float* __restrict__ wih1, const float* __restrict__ whh1,
    const float* __restrict__ bih1, const float* __restrict__ bhh1,
    const float* __restrict__ wfc,  const float* __restrict__ bfc,
    const u16* __restrict__ xbf, u16* __restrict__ h0buf, u16* __restrict__ h1buf,
    float* __restrict__ out, int* stamps)
{
  extern __shared__ u16 smem[];
  u16* Ws_in  = smem;            // [K_in/8][32][8]
  u16* Ws_rec = smem + 16384;    // [64][32][8]

  const int tid    = threadIdx.x;
  const int bid    = blockIdx.x;
  const int layer  = bid >> 7;          // 0..1
  const int lb     = bid & 127;
  const int mhalf  = lb & 1;            // batch half
  const int nc     = lb >> 1;           // 0..63 -> 8 h-cols each
  const int jbase  = nc * 8;
  const int w      = tid >> 6;          // wave 0..3 -> 16 batch rows each
  const int lane   = tid & 63;
  const int l15    = lane & 15;
  const int q      = lane >> 4;
  const int wmbase = mhalf * 64 + w * 16;

  const int K_in = layer ? HDIM : EDIM;
  const float* Wih = layer ? wih1 : wih0;
  const float* Whh = layer ? whh1 : whh0;
  const float* Bih = layer ? bih1 : bih0;
  const float* Bhh = layer ? bhh1 : bhh0;

  // ---- one-time: stage weight slices to LDS as bf16, layout [k/8][n][8] ----
  for (int p = tid; p < 32 * (K_in / 8); p += WGS) {
    int c = p >> 5, n = p & 31;
    int grow = (n >> 3) * HDIM + jbase + (n & 7);     // gate*512 + col
    const float* s = Wih + (size_t)grow * K_in + c * 8;
    u16* d = Ws_in + p * 8;
    #pragma unroll
    for (int e = 0; e < 8; ++e) d[e] = f2bf(s[e]);
  }
  for (int p = tid; p < 32 * (HDIM / 8); p += WGS) {
    int c = p >> 5, n = p & 31;
    int grow = (n >> 3) * HDIM + jbase + (n & 7);
    const float* s = Whh + (size_t)grow * HDIM + c * 8;
    u16* d = Ws_rec + p * 8;
    #pragma unroll
    for (int e = 0; e < 8; ++e) d[e] = f2bf(s[e]);
  }

  // per-lane biases for column cc = l15&7 (lanes n and n+8 duplicate the same column)
  const int cc = l15 & 7;
  const float bi_i = Bih[0*HDIM + jbase + cc] + Bhh[0*HDIM + jbase + cc];
  const float bi_f = Bih[1*HDIM + jbase + cc] + Bhh[1*HDIM + jbase + cc];
  const float bi_g = Bih[2*HDIM + jbase + cc] + Bhh[2*HDIM + jbase + cc];
  const float bi_o = Bih[3*HDIM + jbase + cc] + Bhh[3*HDIM + jbase + cc];

  __syncthreads();   // weights staged; the ONLY workgroup barrier in the kernel

  float cst[4] = {0.f, 0.f, 0.f, 0.f};   // c-state: 4 rows (q*4+r) x col cc
  u16* ownbuf = layer ? h1buf : h0buf;
  const int arow = wmbase + l15;
  // packed per-(q,row) consumer base offset: ((q*128)+arow)*8 ; per kk add 4096
  const size_t cbase = ((size_t)q * 128 + arow) * 8;

  char* sbase = (char*)stamps;
  int* mystamp = (int*)(sbase + (((size_t)mhalf * 4 + w) * 64 + nc) * 8 + (layer ? 4 : 0));
  const u64_t* pollp = (const u64_t*)(sbase + (((size_t)mhalf * 4 + w) * 64 + lane) * 8);

  for (int t = 0; t < T_STEPS; ++t) {
    // x prefetch (layer 0): issued BEFORE the wait so HBM latency hides under poll
    short8 xfr[8];
    if (layer == 0) {
      const u16* xb = xbf + ((size_t)arow * T_STEPS + t) * EDIM + q * 8;
      #pragma unroll
      for (int kk = 0; kk < 8; ++kk) xfr[kk] = *(const short8*)(xb + kk * 32);
    }

    // ======== WAIT: one coalesced 8B/lane poll of the group's 64 {S0,S1} pairs ========
    const int n0 = layer ? (t + 1) : t;
    const int n1 = layer ? t : (t - 3);
    if (n0 > 0) {
      for (;;) {
        u64_t v = __hip_atomic_load(pollp, __ATOMIC_RELAXED, __HIP_MEMORY_SCOPE_AGENT);
        const int s0 = (int)(v & 0xffffffffULL);
        const int s1 = (int)(v >> 32);
        if (__all((s0 >= n0) && (s1 >= n1))) break;
      }
      // No acquire fence needed: all h reads below are cl8 (sc0|sc1, LLC-coherent),
      // issued strictly after the poll branch resolves; producer drained vmcnt(0)
      // before stamping, so observed stamp => h is in LLC.
    }

    // ======== BATCHED LOAD PHASE ========
    u64_t ilo[16], ihi[16];   // input-GEMM frags (layer 1 only)
    u64_t rlo[16], rhi[16];   // recurrent frags
    if (layer == 1) {
      const u16* ab = h0buf + (size_t)(t & 3) * HPITCH + cbase;
      #pragma unroll
      for (int kk = 0; kk < 16; ++kk) {
        ilo[kk] = cl8(ab + kk * 4096);
        ihi[kk] = cl8(ab + kk * 4096 + 4);
      }
    }
    if (t > 0) {
      const u16* rb = ownbuf + (size_t)((t - 1) & 3) * HPITCH + cbase;
      #pragma unroll
      for (int kk = 0; kk < 16; ++kk) {
        rlo[kk] = cl8(rb + kk * 4096);
        rhi[kk] = cl8(rb + kk * 4096 + 4);
      }
    }

    // ======== MFMA PHASE ========
    f32x4 acc0 = {0.f, 0.f, 0.f, 0.f};   // cols n=0..15  (i|f)
    f32x4 acc1 = {0.f, 0.f, 0.f, 0.f};   // cols n=16..31 (g|o)
    auto MM2 = [&](short8 a, const u16* Ws, int kk) {
      const u16* bb = Ws + (kk * 4 + q) * 256 + l15 * 8;
      short8 b0 = *(const short8*)bb;
      short8 b1 = *(const short8*)(bb + 128);
      acc0 = __builtin_amdgcn_mfma_f32_16x16x32_bf16(a, b0, acc0, 0, 0, 0);
      acc1 = __builtin_amdgcn_mfma_f32_16x16x32_bf16(a, b1, acc1, 0, 0, 0);
    };

    if (layer == 0) {
      #pragma unroll
      for (int kk = 0; kk < 8; ++kk) MM2(xfr[kk], Ws_in, kk);
    } else {
      #pragma unroll
      for (int kk = 0; kk < 16; ++kk) MM2(mk8(ilo[kk], ihi[kk]), Ws_in, kk);
    }
    if (t > 0) {
      #pragma unroll
      for (int kk = 0; kk < 16; ++kk) MM2(mk8(rlo[kk], rhi[kk]), Ws_rec, kk);
    }

    // ---- gate epilogue: D layout col=lane&15,row=q*4+r; lanes n<8 hold i,g; n>=8 hold f,o ----
    u16* hw = ownbuf + (size_t)(t & 3) * HPITCH + (size_t)nc * 1024;  // [cg][row][8]
    const bool low = (l15 < 8);
    #pragma unroll
    for (int r = 0; r < 4; ++r) {
      float a0 = acc0[r], a1 = acc1[r];
      float p0 = __shfl_xor(a0, 8);
      float p1 = __shfl_xor(a1, 8);
      float iv = low ? a0 : p0;
      float fv = low ? p0 : a0;
      float gv = low ? a1 : p1;
      float ov = low ? p1 : a1;
      iv = sigm(iv + bi_i);
      fv = sigm(fv + bi_f);
      gv = ftanh(gv + bi_g);
      ov = sigm(ov + bi_o);
      float cn = fv * cst[r] + iv * gv;
      cst[r] = cn;
      float hv = ov * ftanh(cn);
      if (low) cstore2(&hw[(size_t)(wmbase + q * 4 + r) * 8 + cc], f2bf(hv));
    }

    // ======== PUBLISH: wave-wide drain then lane0 stamp (no __syncthreads) ========
    asm volatile("s_waitcnt vmcnt(0)" ::: "memory");
    if (lane == 0)
      __hip_atomic_store(mystamp, t + 1, __ATOMIC_RELAXED, __HIP_MEMORY_SCOPE_AGENT);
  }

  // ---- FC epilogue: out[b] = sigmoid(h2[b,:] . w_fc + b_fc); h1_t=511 is in slot 3 ----
  if (bid == NWG - 1) {
    for (;;) {
      bool ok = true;
      #pragma unroll
      for (int ww = 0; ww < 4; ++ww) {
        u64_t va = __hip_atomic_load((const u64_t*)(sbase + (((size_t)0 * 4 + ww) * 64 + lane) * 8),
                                     __ATOMIC_RELAXED, __HIP_MEMORY_SCOPE_AGENT);
        u64_t vb = __hip_atomic_load((const u64_t*)(sbase + (((size_t)1 * 4 + ww) * 64 + lane) * 8),
                                     __ATOMIC_RELAXED, __HIP_MEMORY_SCOPE_AGENT);
        ok = ok && ((int)(va >> 32) >= T_STEPS) && ((int)(vb >> 32) >= T_STEPS);
      }
      if (__all(ok)) break;
      __builtin_amdgcn_s_sleep(1);
    }
    __builtin_amdgcn_fence(__ATOMIC_ACQUIRE, "agent");
    const int b = tid >> 1, half = tid & 1;
    const u16* hp = h1buf + (size_t)3 * HPITCH;      // slot 511&3 = 3, packed [cg][row][8]
    const float* wf = wfc + half * 256;
    float s = 0.f;
    for (int cg = 0; cg < 32; ++cg) {
      const u16* p = hp + ((size_t)(half * 32 + cg) * 128 + b) * 8;
      #pragma unroll
      for (int e = 0; e < 8; ++e) s += bf2f(p[e]) * wf[cg * 8 + e];
    }
    s += __shfl_xor(s, 1);
    if (half == 0) out[b] = sigm(s + bfc[0]);
  }
}

extern "C" void kernel_launch(void* const* d_in, const int* in_sizes, int n_in,
                              void* d_out, int out_size, void* d_ws, size_t ws_size,
                              hipStream_t stream) {
  (void)in_sizes; (void)n_in; (void)out_size; (void)ws_size;
  const float* x    = (const float*)d_in[0];
  const float* wih0 = (const float*)d_in[1];
  const float* whh0 = (const float*)d_in[2];
  const float* bih0 = (const float*)d_in[3];
  const float* bhh0 = (const float*)d_in[4];
  const float* wih1 = (const float*)d_in[5];
  const float* whh1 = (const float*)d_in[6];
  const float* bih1 = (const float*)d_in[7];
  const float* bhh1 = (const float*)d_in[8];
  const float* wfc  = (const float*)d_in[9];
  const float* bfc  = (const float*)d_in[10];
  float* outp = (float*)d_out;

  char* ws = (char*)d_ws;
  int*  stamps = (int*)(ws + 4096);                            // 4KB: [m][w][nc]{S0,S1}
  u16*  xbf  = (u16*)(ws + 32768);                             // 128*512*256 bf16 = 32 MiB
  u16*  h0   = (u16*)(ws + 32768 + 33554432);                  // 4 slots x 128KB
  u16*  h1   = h0 + NSLOT * HPITCH;                            // 4 slots x 128KB

  hipMemsetAsync(d_ws, 0, 32768, stream);                      // zero stamps

  const int n4 = (BATCH * T_STEPS * EDIM) / 4;                 // 4,194,304
  cvt_bf16_kernel<<<n4 / 256, 256, 0, stream>>>(x, xbf, n4);

  hipFuncSetAttribute((const void*)lstm_kernel,
                      hipFuncAttributeMaxDynamicSharedMemorySize, 65536);

  void* args[] = { (void*)&wih0, (void*)&whh0, (void*)&bih0, (void*)&bhh0,
                   (void*)&wih1, (void*)&whh1, (void*)&bih1, (void*)&bhh1,
                   (void*)&wfc,  (void*)&bfc,
                   (void*)&xbf,  (void*)&h0,   (void*)&h1,
                   (void*)&outp, (void*)&stamps };
  hipLaunchCooperativeKernel((void*)lstm_kernel, dim3(NWG), dim3(WGS),
                             args, 65536, stream);
}

// Round 2
// 2675.704 us; speedup vs baseline: 2.0404x; 2.0404x over previous
//
#include <hip/hip_runtime.h>

using u16    = unsigned short;
using u64_t  = unsigned long long;
using short4v = __attribute__((ext_vector_type(4))) short;
using short8 = __attribute__((ext_vector_type(8))) short;
using f32x4  = __attribute__((ext_vector_type(4))) float;

#define T_STEPS 512
#define BATCH   128
#define HDIM    512
#define EDIM    256
#define NWG     256
#define WGS     256
// packed h: [slot][cg(64)][row(128)][8 cols] bf16 -> 64*128*8 u16 per slot (128KB)
#define HPITCH  65536

__device__ __forceinline__ u16 f2bf(float f) {
  unsigned u = __float_as_uint(f);
  u += 0x7FFFu + ((u >> 16) & 1u);   // RNE
  return (u16)(u >> 16);
}
__device__ __forceinline__ float bf2f(u16 h) {
  return __uint_as_float(((unsigned)h) << 16);
}
__device__ __forceinline__ float sigm(float x) { return 1.0f / (1.0f + __expf(-x)); }
__device__ __forceinline__ float ftanh(float x) { return 1.0f - 2.0f / (__expf(2.0f * x) + 1.0f); }

// ---- coherent (agent-scope, sc0|sc1) accessors: LLC-coherent, bypass L1/L2 ----
__device__ __forceinline__ u64_t cl8(const u16* p) {
  return __hip_atomic_load((const u64_t*)p, __ATOMIC_RELAXED, __HIP_MEMORY_SCOPE_AGENT);
}
__device__ __forceinline__ void cstore2(u16* p, u16 v) {
  __hip_atomic_store(p, v, __ATOMIC_RELAXED, __HIP_MEMORY_SCOPE_AGENT);
}
__device__ __forceinline__ short8 mk8(u64_t lo, u64_t hi) {
  short4v a = __builtin_bit_cast(short4v, lo);
  short4v b = __builtin_bit_cast(short4v, hi);
  return __builtin_shufflevector(a, b, 0, 1, 2, 3, 4, 5, 6, 7);
}

// ---------------- x -> bf16 prep ----------------
__global__ void cvt_bf16_kernel(const float* __restrict__ src, u16* __restrict__ dst, int n4) {
  int i = blockIdx.x * blockDim.x + threadIdx.x;
  if (i >= n4) return;
  float4 v = ((const float4*)src)[i];
  uint2 o;
  o.x = (unsigned)f2bf(v.x) | ((unsigned)f2bf(v.y) << 16);
  o.y = (unsigned)f2bf(v.z) | ((unsigned)f2bf(v.w) << 16);
  ((uint2*)dst)[i] = o;
}

// ---------------- grid barrier: arrival tree + release word ----------------
// Entry __syncthreads drains vmcnt(0) per wave -> all sc1 h-stores are LLC-visible
// before tid0's arrival add. tid0 polls the release word with s_sleep(1); sibling
// waves wait at the exit s_barrier. Monotone epochs; no re-arm.
__device__ __forceinline__ void grid_barrier(int* cnt, int* root, int* rel,
                                             int it, int tid, int bid) {
  __syncthreads();
  if (tid == 0) {
    int* mycnt = cnt + (bid >> 5) * 64;   // 8 sub-counters, 256B apart
    int old = __hip_atomic_fetch_add(mycnt, 1, __ATOMIC_RELAXED, __HIP_MEMORY_SCOPE_AGENT);
    if (old == 32 * (it + 1) - 1) {
      int r = __hip_atomic_fetch_add(root, 1, __ATOMIC_RELAXED, __HIP_MEMORY_SCOPE_AGENT);
      if (r == 8 * (it + 1) - 1)
        __hip_atomic_store(rel, it + 1, __ATOMIC_RELAXED, __HIP_MEMORY_SCOPE_AGENT);
    }
    while (__hip_atomic_load(rel, __ATOMIC_RELAXED, __HIP_MEMORY_SCOPE_AGENT) < it + 1)
      __builtin_amdgcn_s_sleep(1);
  }
  __syncthreads();
}

// ---------------- persistent 2-layer LSTM ----------------
// WG tile: 64 batch rows (mhalf) x 8 h-cols (nc) -> 32 gate rows [i(8) f(8) g(8) o(8)].
// LDS: Ws_in [K_in/8][32][8] bf16 (32KB), Ws_rec [64][32][8] bf16 (32KB) = 64KB dynamic.
// h exchange, hist mode (ws permitting): h[t] gets a UNIQUE slot (no reuse), so
// consumers use PLAIN CACHED 16B loads. A cached line is either absent or correct
// (unique address within the dispatch; L1/L2 are invalidated at dispatch boundaries,
// so no cross-dispatch staleness). Producer sc-stores write through to LLC; the
// barrier orders write->read. First reader per XCD pulls the line into its L2;
// the other ~31 WGs on that XCD hit L2 (34.5 TB/s) instead of hammering the LLC:
// LLC hot-line traffic drops ~24MB/step -> ~3MB/step.
// Fallback (small ws): exact previous behavior - 2-slot ring + cl8 coherent loads.
__global__ void __launch_bounds__(WGS, 1) lstm_kernel(
    const float* __restrict__ wih0, const float* __restrict__ whh0,
    const float* __restrict__ bih0, const float* __restrict__ bhh0,
    const float* __restrict__ wih1, const float* __restrict__ whh1,
    const float* __restrict__ bih1, const float* __restrict__ bhh1,
    const float* __restrict__ wfc,  const float* __restrict__ bfc,
    const u16* __restrict__ xbf, u16* __restrict__ h0buf, u16* __restrict__ h1buf,
    float* __restrict__ out, int* cnt, int* root, int* rel, int hist)
{
  extern __shared__ u16 smem[];
  u16* Ws_in  = smem;            // [K_in/8][32][8]
  u16* Ws_rec = smem + 16384;    // [64][32][8]

  const int tid    = threadIdx.x;
  const int bid    = blockIdx.x;
  const int layer  = bid >> 7;          // 0..1
  const int lb     = bid & 127;
  const int mhalf  = lb & 1;            // batch half
  const int nc     = lb >> 1;           // 0..63 -> 8 h-cols each
  const int jbase  = nc * 8;
  const int w      = tid >> 6;          // wave 0..3 -> 16 batch rows each
  const int lane   = tid & 63;
  const int l15    = lane & 15;
  const int q      = lane >> 4;
  const int wmbase = mhalf * 64 + w * 16;

  const int K_in = layer ? HDIM : EDIM;
  const float* Wih = layer ? wih1 : wih0;
  const float* Whh = layer ? whh1 : whh0;
  const float* Bih = layer ? bih1 : bih0;
  const float* Bhh = layer ? bhh1 : bhh0;

  // ---- one-time: stage weight slices to LDS as bf16, layout [k/8][n][8] ----
  for (int p = tid; p < 32 * (K_in / 8); p += WGS) {
    int c = p >> 5, n = p & 31;
    int grow = (n >> 3) * HDIM + jbase + (n & 7);     // gate*512 + col
    const float* s = Wih + (size_t)grow * K_in + c * 8;
    u16* d = Ws_in + p * 8;
    #pragma unroll
    for (int e = 0; e < 8; ++e) d[e] = f2bf(s[e]);
  }
  for (int p = tid; p < 32 * (HDIM / 8); p += WGS) {
    int c = p >> 5, n = p & 31;
    int grow = (n >> 3) * HDIM + jbase + (n & 7);
    const float* s = Whh + (size_t)grow * HDIM + c * 8;
    u16* d = Ws_rec + p * 8;
    #pragma unroll
    for (int e = 0; e < 8; ++e) d[e] = f2bf(s[e]);
  }

  // per-lane biases for column cc = l15&7 (lanes n and n+8 duplicate the same column)
  const int cc = l15 & 7;
  const float bi_i = Bih[0*HDIM + jbase + cc] + Bhh[0*HDIM + jbase + cc];
  const float bi_f = Bih[1*HDIM + jbase + cc] + Bhh[1*HDIM + jbase + cc];
  const float bi_g = Bih[2*HDIM + jbase + cc] + Bhh[2*HDIM + jbase + cc];
  const float bi_o = Bih[3*HDIM + jbase + cc] + Bhh[3*HDIM + jbase + cc];

  __syncthreads();

  float cst[4] = {0.f, 0.f, 0.f, 0.f};   // c-state: 4 rows (q*4+r) x col cc
  u16* ownbuf = layer ? h1buf : h0buf;
  const int arow = wmbase + l15;
  // packed per-(q,row) consumer base offset: ((q*128)+arow)*8 ; per kk add 4096
  const size_t cbase = ((size_t)q * 128 + arow) * 8;

  for (int it = 0; it <= T_STEPS; ++it) {
    const int t = layer ? (it - 1) : it;
    if (t >= 0 && t < T_STEPS) {
      // ======== BATCHED LOAD PHASE: all h-frag loads issued back-to-back ========
      short8 ifr[16];           // input-GEMM frags (layer 1 only; layer 0 uses xfr)
      short8 rfr[16];           // recurrent frags
      short8 xfr[8];            // layer-0 x frags (plain cached loads)

      if (layer == 1) {
        const u16* ab = h0buf + (size_t)(hist ? t : (t & 1)) * HPITCH + cbase;
        if (hist) {
          #pragma unroll
          for (int kk = 0; kk < 16; ++kk)
            ifr[kk] = *(const short8*)(ab + kk * 4096);
        } else {
          #pragma unroll
          for (int kk = 0; kk < 16; ++kk)
            ifr[kk] = mk8(cl8(ab + kk * 4096), cl8(ab + kk * 4096 + 4));
        }
      }
      if (t > 0) {
        const u16* rb = ownbuf + (size_t)(hist ? (t - 1) : ((t - 1) & 1)) * HPITCH + cbase;
        if (hist) {
          #pragma unroll
          for (int kk = 0; kk < 16; ++kk)
            rfr[kk] = *(const short8*)(rb + kk * 4096);
        } else {
          #pragma unroll
          for (int kk = 0; kk < 16; ++kk)
            rfr[kk] = mk8(cl8(rb + kk * 4096), cl8(rb + kk * 4096 + 4));
        }
      }
      if (layer == 0) {
        const u16* xb = xbf + ((size_t)arow * T_STEPS + t) * EDIM + q * 8;
        #pragma unroll
        for (int kk = 0; kk < 8; ++kk) xfr[kk] = *(const short8*)(xb + kk * 32);
      }

      // ======== MFMA PHASE ========
      f32x4 acc0 = {0.f, 0.f, 0.f, 0.f};   // cols n=0..15  (i|f)
      f32x4 acc1 = {0.f, 0.f, 0.f, 0.f};   // cols n=16..31 (g|o)
      auto MM2 = [&](short8 a, const u16* Ws, int kk) {
        const u16* bb = Ws + (kk * 4 + q) * 256 + l15 * 8;
        short8 b0 = *(const short8*)bb;
        short8 b1 = *(const short8*)(bb + 128);
        acc0 = __builtin_amdgcn_mfma_f32_16x16x32_bf16(a, b0, acc0, 0, 0, 0);
        acc1 = __builtin_amdgcn_mfma_f32_16x16x32_bf16(a, b1, acc1, 0, 0, 0);
      };

      if (layer == 0) {
        #pragma unroll
        for (int kk = 0; kk < 8; ++kk) MM2(xfr[kk], Ws_in, kk);
      } else {
        #pragma unroll
        for (int kk = 0; kk < 16; ++kk) MM2(ifr[kk], Ws_in, kk);
      }
      if (t > 0) {
        #pragma unroll
        for (int kk = 0; kk < 16; ++kk) MM2(rfr[kk], Ws_rec, kk);
      }

      // ---- gate epilogue: D layout col=lane&15,row=q*4+r; lanes n<8 hold i,g; n>=8 hold f,o ----
      u16* hw = ownbuf + (size_t)(hist ? t : (t & 1)) * HPITCH + (size_t)nc * 1024;  // [cg][row][8]
      const bool low = (l15 < 8);
      #pragma unroll
      for (int r = 0; r < 4; ++r) {
        float a0 = acc0[r], a1 = acc1[r];
        float p0 = __shfl_xor(a0, 8);
        float p1 = __shfl_xor(a1, 8);
        float iv = low ? a0 : p0;
        float fv = low ? p0 : a0;
        float gv = low ? a1 : p1;
        float ov = low ? p1 : a1;
        iv = sigm(iv + bi_i);
        fv = sigm(fv + bi_f);
        gv = ftanh(gv + bi_g);
        ov = sigm(ov + bi_o);
        float cn = fv * cst[r] + iv * gv;
        cst[r] = cn;
        float hv = ov * ftanh(cn);
        if (low) cstore2(&hw[(size_t)(wmbase + q * 4 + r) * 8 + cc], f2bf(hv));
      }
    }
    grid_barrier(cnt, root, rel, it, tid, bid);
  }

  // ---- FC epilogue: out[b] = sigmoid(h2[b,:] . w_fc + b_fc) ----
  if (bid == NWG - 1) {
    __builtin_amdgcn_fence(__ATOMIC_ACQUIRE, "agent");
    const int b = tid >> 1, half = tid & 1;
    const u16* hp = h1buf + (size_t)(hist ? (T_STEPS - 1) : 1) * HPITCH;  // last h1 slot
    const float* wf = wfc + half * 256;
    float s = 0.f;
    for (int cg = 0; cg < 32; ++cg) {
      const u16* p = hp + ((size_t)(half * 32 + cg) * 128 + b) * 8;
      #pragma unroll
      for (int e = 0; e < 8; ++e) s += bf2f(p[e]) * wf[cg * 8 + e];
    }
    s += __shfl_xor(s, 1);
    if (half == 0) out[b] = sigm(s + bfc[0]);
  }
}

extern "C" void kernel_launch(void* const* d_in, const int* in_sizes, int n_in,
                              void* d_out, int out_size, void* d_ws, size_t ws_size,
                              hipStream_t stream) {
  (void)in_sizes; (void)n_in; (void)out_size;
  const float* x    = (const float*)d_in[0];
  const float* wih0 = (const float*)d_in[1];
  const float* whh0 = (const float*)d_in[2];
  const float* bih0 = (const float*)d_in[3];
  const float* bhh0 = (const float*)d_in[4];
  const float* wih1 = (const float*)d_in[5];
  const float* whh1 = (const float*)d_in[6];
  const float* bih1 = (const float*)d_in[7];
  const float* bhh1 = (const float*)d_in[8];
  const float* wfc  = (const float*)d_in[9];
  const float* bfc  = (const float*)d_in[10];
  float* outp = (float*)d_out;

  char* ws = (char*)d_ws;
  int*  cnt  = (int*)ws;                                       // 8 sub-counters, 256B apart
  int*  root = (int*)(ws + 2048);                              // root counter
  int*  rel  = (int*)(ws + 2176);                              // release epoch word
  u16*  xbf  = (u16*)(ws + 4096);                              // 128*512*256 bf16 = 32 MiB
  u16*  h0   = (u16*)(ws + 4096 + 33554432);

  // hist mode: h[t] at a unique slot (512 slots x 128KB per layer) -> plain cached
  // consumer loads (L2 broadcast). Needs ~168MB of workspace; else fall back to the
  // verified 2-slot + coherent-load scheme.
  const size_t need_hist = 4096ull + 33554432ull + 2ull * T_STEPS * HPITCH * sizeof(u16);
  const int hist = (ws_size >= need_hist) ? 1 : 0;
  const size_t slots = hist ? T_STEPS : 2;
  u16* h1 = h0 + slots * HPITCH;

  hipMemsetAsync(d_ws, 0, 4096, stream);                       // zero barrier state

  const int n4 = (BATCH * T_STEPS * EDIM) / 4;                 // 4,194,304
  cvt_bf16_kernel<<<n4 / 256, 256, 0, stream>>>(x, xbf, n4);

  hipFuncSetAttribute((const void*)lstm_kernel,
                      hipFuncAttributeMaxDynamicSharedMemorySize, 65536);

  void* args[] = { (void*)&wih0, (void*)&whh0, (void*)&bih0, (void*)&bhh0,
                   (void*)&wih1, (void*)&whh1, (void*)&bih1, (void*)&bhh1,
                   (void*)&wfc,  (void*)&bfc,
                   (void*)&xbf,  (void*)&h0,   (void*)&h1,
                   (void*)&outp, (void*)&cnt,  (void*)&root, (void*)&rel,
                   (void*)&hist };
  hipLaunchCooperativeKernel((void*)lstm_kernel, dim3(NWG), dim3(WGS),
                             args, 65536, stream);
}

// Round 3
// 2398.506 us; speedup vs baseline: 2.2762x; 1.1156x over previous
//
#include <hip/hip_runtime.h>

using u16    = unsigned short;
using u64_t  = unsigned long long;
using short4v = __attribute__((ext_vector_type(4))) short;
using short8 = __attribute__((ext_vector_type(8))) short;
using f32x4  = __attribute__((ext_vector_type(4))) float;

#define T_STEPS 512
#define BATCH   128
#define HDIM    512
#define EDIM    256
#define NWG     256
#define WGS     256
// packed h: [slot][cg(64)][row(128)][8 cols] bf16 -> 64*128*8 u16 per slot (128KB)
#define HPITCH  65536

__device__ __forceinline__ u16 f2bf(float f) {
  unsigned u = __float_as_uint(f);
  u += 0x7FFFu + ((u >> 16) & 1u);   // RNE
  return (u16)(u >> 16);
}
__device__ __forceinline__ float bf2f(u16 h) {
  return __uint_as_float(((unsigned)h) << 16);
}
__device__ __forceinline__ float sigm(float x) { return 1.0f / (1.0f + __expf(-x)); }
__device__ __forceinline__ float ftanh(float x) { return 1.0f - 2.0f / (__expf(2.0f * x) + 1.0f); }

// ---- coherent (agent-scope, sc0|sc1) accessors: LLC-coherent, bypass L1/L2 ----
__device__ __forceinline__ u64_t cl8(const u16* p) {
  return __hip_atomic_load((const u64_t*)p, __ATOMIC_RELAXED, __HIP_MEMORY_SCOPE_AGENT);
}
__device__ __forceinline__ void cstore2(u16* p, u16 v) {
  __hip_atomic_store(p, v, __ATOMIC_RELAXED, __HIP_MEMORY_SCOPE_AGENT);
}
__device__ __forceinline__ int ld4(const int* p) {
  return __hip_atomic_load(p, __ATOMIC_RELAXED, __HIP_MEMORY_SCOPE_AGENT);
}
__device__ __forceinline__ short8 mk8(u64_t lo, u64_t hi) {
  short4v a = __builtin_bit_cast(short4v, lo);
  short4v b = __builtin_bit_cast(short4v, hi);
  return __builtin_shufflevector(a, b, 0, 1, 2, 3, 4, 5, 6, 7);
}

// ---------------- x -> bf16 prep ----------------
__global__ void cvt_bf16_kernel(const float* __restrict__ src, u16* __restrict__ dst, int n4) {
  int i = blockIdx.x * blockDim.x + threadIdx.x;
  if (i >= n4) return;
  float4 v = ((const float4*)src)[i];
  uint2 o;
  o.x = (unsigned)f2bf(v.x) | ((unsigned)f2bf(v.y) << 16);
  o.y = (unsigned)f2bf(v.z) | ((unsigned)f2bf(v.w) << 16);
  ((uint2*)dst)[i] = o;
}

// ---------------- sync state layout (byte offsets into sync base) ----------------
//     0 .. 16383 : group sub-counters  : gid*4096 + sub*256   (4 groups x 8 subs)
// 16384 .. 20479 : group root counters : 16384 + gid*256
// 20480 .. 28671 : release lines       : 20480 + (gid*8+line)*256  (epoch ints)
// 28672 .. 32767 : fallback full-grid barrier: cnt @28672 (8x256B), root @30720, rel @30848
// All zeroed by host. Epochs are monotone; no re-arm.

// ---------------- full grid barrier (hist=0 fallback only) ----------------
__device__ __forceinline__ void grid_barrier(int* cnt, int* root, int* rel,
                                             int it, int tid, int bid) {
  __syncthreads();
  if (tid == 0) {
    int* mycnt = cnt + (bid >> 5) * 64;   // 8 sub-counters, 256B apart
    int old = __hip_atomic_fetch_add(mycnt, 1, __ATOMIC_RELAXED, __HIP_MEMORY_SCOPE_AGENT);
    if (old == 32 * (it + 1) - 1) {
      int r = __hip_atomic_fetch_add(root, 1, __ATOMIC_RELAXED, __HIP_MEMORY_SCOPE_AGENT);
      if (r == 8 * (it + 1) - 1)
        __hip_atomic_store(rel, it + 1, __ATOMIC_RELAXED, __HIP_MEMORY_SCOPE_AGENT);
    }
    while (__hip_atomic_load(rel, __ATOMIC_RELAXED, __HIP_MEMORY_SCOPE_AGENT) < it + 1)
      __builtin_amdgcn_s_sleep(1);
  }
  __syncthreads();
}

// ---------------- persistent 2-layer LSTM ----------------
// hist mode: h[t] at a UNIQUE slot -> no slot-reuse anti-deps -> the full grid
// barrier decomposes into 4 INDEPENDENT group barriers (layer x mhalf, 64 WGs).
// L0 groups never wait on L1; L1 waits {own-group E>=t, paired-L0 E>=t+1}.
// Release is fanned out to 8 lines/group (<=16 pollers/line) to kill the
// single-hot-LLC-line serialization that dominated the 256-WG barrier.
// Consumers use PLAIN CACHED loads for h (unique addresses -> a cached line is
// absent or correct; verified passing in the previous round). Producers sc-store
// h; __syncthreads drains vmcnt before tid0's arrival atomic publishes.
__global__ void __launch_bounds__(WGS, 1) lstm_kernel(
    const float* __restrict__ wih0, const float* __restrict__ whh0,
    const float* __restrict__ bih0, const float* __restrict__ bhh0,
    const float* __restrict__ wih1, const float* __restrict__ whh1,
    const float* __restrict__ bih1, const float* __restrict__ bhh1,
    const float* __restrict__ wfc,  const float* __restrict__ bfc,
    const u16* __restrict__ xbf, u16* __restrict__ h0buf, u16* __restrict__ h1buf,
    float* __restrict__ out, int* syncp, int hist)
{
  extern __shared__ u16 smem[];
  u16* Ws_in  = smem;            // [K_in/8][32][8]
  u16* Ws_rec = smem + 16384;    // [64][32][8]

  const int tid    = threadIdx.x;
  const int bid    = blockIdx.x;
  const int layer  = bid >> 7;          // 0..1
  const int lb     = bid & 127;
  const int mhalf  = lb & 1;            // batch half
  const int nc     = lb >> 1;           // 0..63 -> 8 h-cols each
  const int jbase  = nc * 8;
  const int w      = tid >> 6;          // wave 0..3 -> 16 batch rows each
  const int lane   = tid & 63;
  const int l15    = lane & 15;
  const int q      = lane >> 4;
  const int wmbase = mhalf * 64 + w * 16;
  const int gid    = layer * 2 + mhalf; // sync group

  char* sb = (char*)syncp;

  const int K_in = layer ? HDIM : EDIM;
  const float* Wih = layer ? wih1 : wih0;
  const float* Whh = layer ? whh1 : whh0;
  const float* Bih = layer ? bih1 : bih0;
  const float* Bhh = layer ? bhh1 : bhh0;

  // ---- one-time: stage weight slices to LDS as bf16, layout [k/8][n][8] ----
  for (int p = tid; p < 32 * (K_in / 8); p += WGS) {
    int c = p >> 5, n = p & 31;
    int grow = (n >> 3) * HDIM + jbase + (n & 7);     // gate*512 + col
    const float* s = Wih + (size_t)grow * K_in + c * 8;
    u16* d = Ws_in + p * 8;
    #pragma unroll
    for (int e = 0; e < 8; ++e) d[e] = f2bf(s[e]);
  }
  for (int p = tid; p < 32 * (HDIM / 8); p += WGS) {
    int c = p >> 5, n = p & 31;
    int grow = (n >> 3) * HDIM + jbase + (n & 7);
    const float* s = Whh + (size_t)grow * HDIM + c * 8;
    u16* d = Ws_rec + p * 8;
    #pragma unroll
    for (int e = 0; e < 8; ++e) d[e] = f2bf(s[e]);
  }

  // per-lane biases for column cc = l15&7 (lanes n and n+8 duplicate the same column)
  const int cc = l15 & 7;
  const float bi_i = Bih[0*HDIM + jbase + cc] + Bhh[0*HDIM + jbase + cc];
  const float bi_f = Bih[1*HDIM + jbase + cc] + Bhh[1*HDIM + jbase + cc];
  const float bi_g = Bih[2*HDIM + jbase + cc] + Bhh[2*HDIM + jbase + cc];
  const float bi_o = Bih[3*HDIM + jbase + cc] + Bhh[3*HDIM + jbase + cc];

  __syncthreads();

  float cst[4] = {0.f, 0.f, 0.f, 0.f};   // c-state: 4 rows (q*4+r) x col cc
  u16* ownbuf = layer ? h1buf : h0buf;
  const int arow = wmbase + l15;
  // packed per-(q,row) consumer base offset: ((q*128)+arow)*8 ; per kk add 4096
  const size_t cbase = ((size_t)q * 128 + arow) * 8;

  // MFMA helper: 4 accumulator chains (A/B by kk parity) so dependent-MFMA
  // latency is covered (single-chain 32-deep dep chain stalls ~16cy each).
  auto MM2 = [&](short8 a, const u16* Ws, int kk, f32x4& A0, f32x4& A1) {
    const u16* bb = Ws + (kk * 4 + q) * 256 + l15 * 8;
    short8 b0 = *(const short8*)bb;
    short8 b1 = *(const short8*)(bb + 128);
    A0 = __builtin_amdgcn_mfma_f32_16x16x32_bf16(a, b0, A0, 0, 0, 0);
    A1 = __builtin_amdgcn_mfma_f32_16x16x32_bf16(a, b1, A1, 0, 0, 0);
  };

  if (hist) {
    // ================= decoupled group-barrier main loop =================
    const int* own_rel = (const int*)(sb + 20480 + (size_t)(gid * 8 + (nc >> 3)) * 256);
    const int* l0_rel  = (const int*)(sb + 20480 + (size_t)(mhalf * 8 + (nc >> 3)) * 256);
    int* sub_cnt = (int*)(sb + (size_t)gid * 4096 + (size_t)(nc >> 3) * 256);
    int* root_cnt = (int*)(sb + 16384 + (size_t)gid * 256);

    for (int t = 0; t < T_STEPS; ++t) {
      // x prefetch (layer 0) BEFORE the wait: HBM/L2 latency hides under poll
      short8 xfr[8];
      if (layer == 0) {
        const u16* xb = xbf + ((size_t)arow * T_STEPS + t) * EDIM + q * 8;
        #pragma unroll
        for (int kk = 0; kk < 8; ++kk) xfr[kk] = *(const short8*)(xb + kk * 32);
      }

      // ---- WAIT (tid0 busy-polls its 8-poller release line; waves at s_barrier) ----
      if (tid == 0) {
        if (layer == 0) {
          if (t > 0) while (ld4(own_rel) < t) {}
        } else {
          while (ld4(own_rel) < t || ld4(l0_rel) < t + 1) {}
        }
      }
      __syncthreads();

      // ---- BATCHED LOAD PHASE (plain cached: unique slot addresses) ----
      short8 ifr[16];
      short8 rfr[16];
      if (layer == 1) {
        const u16* ab = h0buf + (size_t)t * HPITCH + cbase;
        #pragma unroll
        for (int kk = 0; kk < 16; ++kk) ifr[kk] = *(const short8*)(ab + kk * 4096);
      }
      if (t > 0) {
        const u16* rb = ownbuf + (size_t)(t - 1) * HPITCH + cbase;
        #pragma unroll
        for (int kk = 0; kk < 16; ++kk) rfr[kk] = *(const short8*)(rb + kk * 4096);
      }

      // ---- MFMA PHASE ----
      f32x4 a0A = {0,0,0,0}, a1A = {0,0,0,0}, a0B = {0,0,0,0}, a1B = {0,0,0,0};
      if (layer == 0) {
        #pragma unroll
        for (int kk = 0; kk < 8; ++kk)
          MM2(xfr[kk], Ws_in, kk, (kk & 1) ? a0B : a0A, (kk & 1) ? a1B : a1A);
      } else {
        #pragma unroll
        for (int kk = 0; kk < 16; ++kk)
          MM2(ifr[kk], Ws_in, kk, (kk & 1) ? a0B : a0A, (kk & 1) ? a1B : a1A);
      }
      if (t > 0) {
        #pragma unroll
        for (int kk = 0; kk < 16; ++kk)
          MM2(rfr[kk], Ws_rec, kk, (kk & 1) ? a0B : a0A, (kk & 1) ? a1B : a1A);
      }
      f32x4 acc0 = a0A + a0B;
      f32x4 acc1 = a1A + a1B;

      // ---- gate epilogue ----
      u16* hw = ownbuf + (size_t)t * HPITCH + (size_t)nc * 1024;  // [cg][row][8]
      const bool low = (l15 < 8);
      #pragma unroll
      for (int r = 0; r < 4; ++r) {
        float a0 = acc0[r], a1 = acc1[r];
        float p0 = __shfl_xor(a0, 8);
        float p1 = __shfl_xor(a1, 8);
        float iv = low ? a0 : p0;
        float fv = low ? p0 : a0;
        float gv = low ? a1 : p1;
        float ov = low ? p1 : a1;
        iv = sigm(iv + bi_i);
        fv = sigm(fv + bi_f);
        gv = ftanh(gv + bi_g);
        ov = sigm(ov + bi_o);
        float cn = fv * cst[r] + iv * gv;
        cst[r] = cn;
        float hv = ov * ftanh(cn);
        if (low) cstore2(&hw[(size_t)(wmbase + q * 4 + r) * 8 + cc], f2bf(hv));
      }

      // ---- PUBLISH: __syncthreads drains vmcnt per wave; tid0 walks the tree ----
      __syncthreads();
      if (tid == 0) {
        int old = __hip_atomic_fetch_add(sub_cnt, 1, __ATOMIC_RELAXED, __HIP_MEMORY_SCOPE_AGENT);
        if (old == 8 * (t + 1) - 1) {
          int r = __hip_atomic_fetch_add(root_cnt, 1, __ATOMIC_RELAXED, __HIP_MEMORY_SCOPE_AGENT);
          if (r == 8 * (t + 1) - 1) {
            #pragma unroll
            for (int l = 0; l < 8; ++l)
              __hip_atomic_store((int*)(sb + 20480 + (size_t)(gid * 8 + l) * 256), t + 1,
                                 __ATOMIC_RELAXED, __HIP_MEMORY_SCOPE_AGENT);
          }
        }
      }
    }

    // ---- FC epilogue: wait both L1 groups done, then out = sigmoid(h2.wfc+bfc) ----
    if (bid == NWG - 1) {
      const int* g2 = (const int*)(sb + 20480 + (size_t)(2 * 8 + 0) * 256);
      const int* g3 = (const int*)(sb + 20480 + (size_t)(3 * 8 + 0) * 256);
      if (tid == 0) { while (ld4(g2) < T_STEPS || ld4(g3) < T_STEPS) {} }
      __syncthreads();
      __builtin_amdgcn_fence(__ATOMIC_ACQUIRE, "agent");
      const int b = tid >> 1, half = tid & 1;
      const u16* hp = h1buf + (size_t)(T_STEPS - 1) * HPITCH;
      const float* wf = wfc + half * 256;
      float s = 0.f;
      for (int cg = 0; cg < 32; ++cg) {
        const u16* p = hp + ((size_t)(half * 32 + cg) * 128 + b) * 8;
        #pragma unroll
        for (int e = 0; e < 8; ++e) s += bf2f(p[e]) * wf[cg * 8 + e];
      }
      s += __shfl_xor(s, 1);
      if (half == 0) out[b] = sigm(s + bfc[0]);
    }
    return;
  }

  // ================= hist=0 fallback: rigid full-grid barrier, 2-slot ring =================
  int* f_cnt  = (int*)(sb + 28672);
  int* f_root = (int*)(sb + 30720);
  int* f_rel  = (int*)(sb + 30848);
  for (int it = 0; it <= T_STEPS; ++it) {
    const int t = layer ? (it - 1) : it;
    if (t >= 0 && t < T_STEPS) {
      short8 ifr[16];
      short8 rfr[16];
      short8 xfr[8];
      if (layer == 1) {
        const u16* ab = h0buf + (size_t)(t & 1) * HPITCH + cbase;
        #pragma unroll
        for (int kk = 0; kk < 16; ++kk)
          ifr[kk] = mk8(cl8(ab + kk * 4096), cl8(ab + kk * 4096 + 4));
      }
      if (t > 0) {
        const u16* rb = ownbuf + (size_t)((t - 1) & 1) * HPITCH + cbase;
        #pragma unroll
        for (int kk = 0; kk < 16; ++kk)
          rfr[kk] = mk8(cl8(rb + kk * 4096), cl8(rb + kk * 4096 + 4));
      }
      if (layer == 0) {
        const u16* xb = xbf + ((size_t)arow * T_STEPS + t) * EDIM + q * 8;
        #pragma unroll
        for (int kk = 0; kk < 8; ++kk) xfr[kk] = *(const short8*)(xb + kk * 32);
      }

      f32x4 a0A = {0,0,0,0}, a1A = {0,0,0,0}, a0B = {0,0,0,0}, a1B = {0,0,0,0};
      if (layer == 0) {
        #pragma unroll
        for (int kk = 0; kk < 8; ++kk)
          MM2(xfr[kk], Ws_in, kk, (kk & 1) ? a0B : a0A, (kk & 1) ? a1B : a1A);
      } else {
        #pragma unroll
        for (int kk = 0; kk < 16; ++kk)
          MM2(ifr[kk], Ws_in, kk, (kk & 1) ? a0B : a0A, (kk & 1) ? a1B : a1A);
      }
      if (t > 0) {
        #pragma unroll
        for (int kk = 0; kk < 16; ++kk)
          MM2(rfr[kk], Ws_rec, kk, (kk & 1) ? a0B : a0A, (kk & 1) ? a1B : a1A);
      }
      f32x4 acc0 = a0A + a0B;
      f32x4 acc1 = a1A + a1B;

      u16* hw = ownbuf + (size_t)(t & 1) * HPITCH + (size_t)nc * 1024;
      const bool low = (l15 < 8);
      #pragma unroll
      for (int r = 0; r < 4; ++r) {
        float a0 = acc0[r], a1 = acc1[r];
        float p0 = __shfl_xor(a0, 8);
        float p1 = __shfl_xor(a1, 8);
        float iv = low ? a0 : p0;
        float fv = low ? p0 : a0;
        float gv = low ? a1 : p1;
        float ov = low ? p1 : a1;
        iv = sigm(iv + bi_i);
        fv = sigm(fv + bi_f);
        gv = ftanh(gv + bi_g);
        ov = sigm(ov + bi_o);
        float cn = fv * cst[r] + iv * gv;
        cst[r] = cn;
        float hv = ov * ftanh(cn);
        if (low) cstore2(&hw[(size_t)(wmbase + q * 4 + r) * 8 + cc], f2bf(hv));
      }
    }
    grid_barrier(f_cnt, f_root, f_rel, it, tid, bid);
  }
  if (bid == NWG - 1) {
    __builtin_amdgcn_fence(__ATOMIC_ACQUIRE, "agent");
    const int b = tid >> 1, half = tid & 1;
    const u16* hp = h1buf + (size_t)1 * HPITCH;
    const float* wf = wfc + half * 256;
    float s = 0.f;
    for (int cg = 0; cg < 32; ++cg) {
      const u16* p = hp + ((size_t)(half * 32 + cg) * 128 + b) * 8;
      #pragma unroll
      for (int e = 0; e < 8; ++e) s += bf2f(p[e]) * wf[cg * 8 + e];
    }
    s += __shfl_xor(s, 1);
    if (half == 0) out[b] = sigm(s + bfc[0]);
  }
}

extern "C" void kernel_launch(void* const* d_in, const int* in_sizes, int n_in,
                              void* d_out, int out_size, void* d_ws, size_t ws_size,
                              hipStream_t stream) {
  (void)in_sizes; (void)n_in; (void)out_size;
  const float* x    = (const float*)d_in[0];
  const float* wih0 = (const float*)d_in[1];
  const float* whh0 = (const float*)d_in[2];
  const float* bih0 = (const float*)d_in[3];
  const float* bhh0 = (const float*)d_in[4];
  const float* wih1 = (const float*)d_in[5];
  const float* whh1 = (const float*)d_in[6];
  const float* bih1 = (const float*)d_in[7];
  const float* bhh1 = (const float*)d_in[8];
  const float* wfc  = (const float*)d_in[9];
  const float* bfc  = (const float*)d_in[10];
  float* outp = (float*)d_out;

  char* ws = (char*)d_ws;
  int*  syncp = (int*)ws;                                      // 32KB sync state
  u16*  xbf   = (u16*)(ws + 32768);                            // 128*512*256 bf16 = 32 MiB
  u16*  h0    = (u16*)(ws + 32768 + 33554432);

  // hist mode: h[t] at a unique slot (512 x 128KB per layer) -> plain cached loads
  // + decoupled per-group barriers. Else: 2-slot ring + full grid barrier.
  const size_t need_hist = 32768ull + 33554432ull + 2ull * T_STEPS * HPITCH * sizeof(u16);
  const int hist = (ws_size >= need_hist) ? 1 : 0;
  const size_t slots = hist ? T_STEPS : 2;
  u16* h1 = h0 + slots * HPITCH;

  hipMemsetAsync(d_ws, 0, 32768, stream);                      // zero sync state

  const int n4 = (BATCH * T_STEPS * EDIM) / 4;                 // 4,194,304
  cvt_bf16_kernel<<<n4 / 256, 256, 0, stream>>>(x, xbf, n4);

  hipFuncSetAttribute((const void*)lstm_kernel,
                      hipFuncAttributeMaxDynamicSharedMemorySize, 65536);

  void* args[] = { (void*)&wih0, (void*)&whh0, (void*)&bih0, (void*)&bhh0,
                   (void*)&wih1, (void*)&whh1, (void*)&bih1, (void*)&bhh1,
                   (void*)&wfc,  (void*)&bfc,
                   (void*)&xbf,  (void*)&h0,   (void*)&h1,
                   (void*)&outp, (void*)&syncp, (void*)&hist };
  hipLaunchCooperativeKernel((void*)lstm_kernel, dim3(NWG), dim3(WGS),
                             args, 65536, stream);
}